// Round 4
// baseline (1982.691 us; speedup 1.0000x reference)
//
#include <hip/hip_runtime.h>

#define N_NODES 10000
#define N_EDGES 160000
#define NUM_FEAT 14
#define EDGE_DIM 4
#define DIM 64
#define HID 128
#define LAYERS 28

#define NEG_INF (-__builtin_inff())

// ---------------- CSR build ----------------

__global__ __launch_bounds__(256) void k_zero(int* __restrict__ p, int n) {
  int i = blockIdx.x * 256 + threadIdx.x;
  if (i < n) p[i] = 0;
}

__global__ __launch_bounds__(256) void k_hist(const int* __restrict__ dst, int* __restrict__ cur) {
  int e = blockIdx.x * 256 + threadIdx.x;
  if (e < N_EDGES) atomicAdd(&cur[dst[e]], 1);
}

__global__ __launch_bounds__(256) void k_scan(int* __restrict__ cur, int* __restrict__ off) {
  __shared__ int part[256];
  int t = threadIdx.x;
  const int CH = 40;
  int base = t * CH;
  int s = 0;
  for (int i = 0; i < CH; i++) {
    int idx = base + i;
    if (idx < N_NODES) s += cur[idx];
  }
  part[t] = s;
  __syncthreads();
  for (int ofs = 1; ofs < 256; ofs <<= 1) {
    int tmp = (t >= ofs) ? part[t - ofs] : 0;
    __syncthreads();
    part[t] += tmp;
    __syncthreads();
  }
  int run = part[t] - s;
  for (int i = 0; i < CH; i++) {
    int idx = base + i;
    if (idx < N_NODES) {
      int d = cur[idx];
      off[idx] = run;
      cur[idx] = run;
      run += d;
    }
  }
  if (t == 255) off[N_NODES] = part[255];
}

__global__ __launch_bounds__(256) void k_scatter(const int* __restrict__ dst, int* __restrict__ cur,
                                                 int* __restrict__ eids) {
  int e = blockIdx.x * 256 + threadIdx.x;
  if (e < N_EDGES) {
    int p = atomicAdd(&cur[dst[e]], 1);
    eids[p] = e;
  }
}

// wave-per-node bitonic sort of edge ids, then gather src/eattr into slot order.
__global__ __launch_bounds__(256) void k_sortgather(
    const int* __restrict__ off, const int* __restrict__ eids,
    const int* __restrict__ src, const float4* __restrict__ eattr,
    int* __restrict__ src_s, float4* __restrict__ eattr_s) {
  int node = blockIdx.x * 4 + (threadIdx.x >> 6);
  int lane = threadIdx.x & 63;
  if (node >= N_NODES) return;
  int a = off[node];
  int d = off[node + 1] - a;
  if (d <= 64) {
    int key = (lane < d) ? eids[a + lane] : 0x7fffffff;
#pragma unroll
    for (int k = 2; k <= 64; k <<= 1) {
      for (int j = k >> 1; j > 0; j >>= 1) {
        int p = __shfl_xor(key, j);
        bool dirUp = ((lane & k) == 0);
        bool isLower = ((lane & j) == 0);
        key = ((isLower == dirUp) ? min(key, p) : max(key, p));
      }
    }
    if (lane < d) {
      int e = key;
      src_s[a + lane] = src[e];
      eattr_s[a + lane] = eattr[e];
    }
  } else {
    for (int i = lane; i < d; i += 64) {
      int e = eids[a + i];
      int r = 0;
      for (int j = 0; j < d; j++) r += (eids[a + j] < e) ? 1 : 0;
      src_s[a + r] = src[e];
      eattr_s[a + r] = eattr[e];
    }
  }
}

// ---------------- node encoder ----------------

__global__ __launch_bounds__(256) void k_enc(const float* __restrict__ x, const float* __restrict__ Wn,
                                             const float* __restrict__ bn, float* __restrict__ hc,
                                             float* __restrict__ u) {
  int gid = blockIdx.x * 256 + threadIdx.x;
  if (gid >= N_NODES * DIM) return;
  int n = gid >> 6, j = gid & 63;
  float acc = bn[j];
#pragma unroll
  for (int k = 0; k < NUM_FEAT; k++) acc += x[n * NUM_FEAT + k] * Wn[k * DIM + j];
  hc[gid] = acc;
  u[gid] = acc;
}

// ---------------- fused layer kernel ----------------
// TILE=20 nodes/block, 320 threads (5 waves). Wave wv owns nodes wv*4..wv*4+3
// end-to-end: edge agg (batch-16 tree softmax) -> h in LDS -> GEMM1 (2 cols/lane)
// -> LN via shfl_xor -> z in LDS -> GEMM2 (1 col/lane) -> residual -> LN2 via shfl.
// h/z LDS reads are wave-uniform-address broadcasts (conflict-free). W1/W2 are
// loaded to regs at entry (latency hidden under phase 1), ds_written before the
// single __syncthreads. One barrier per layer total.

#define TILE 20
#define NBLK (N_NODES / TILE)  // 500, exact

template <bool GUARD>
__device__ __forceinline__ void agg_batch(
    const int* __restrict__ src_s, const float4* __restrict__ eattr_s,
    const float* __restrict__ uin, int base, int rem, int lane,
    float be, float we0, float we1, float we2, float we3, float tv,
    float& m, float& sum, float& acc) {
  float msg[16], lg[16];
#pragma unroll
  for (int j = 0; j < 16; j++) {
    if (!GUARD || j < rem) {
      int sn = src_s[base + j];
      float4 ev = eattr_s[base + j];
      float mv = fmaxf(uin[(sn << 6) + lane] + be + ev.x * we0 + ev.y * we1 +
                       ev.z * we2 + ev.w * we3, 0.f) + 1e-7f;
      msg[j] = mv;
      lg[j] = mv * tv;
    } else {
      msg[j] = 0.f;
      lg[j] = NEG_INF;
    }
  }
  // batch max (tree)
  float t8[8];
#pragma unroll
  for (int j = 0; j < 8; j++) t8[j] = fmaxf(lg[j], lg[j + 8]);
#pragma unroll
  for (int j = 0; j < 4; j++) t8[j] = fmaxf(t8[j], t8[j + 4]);
  float bm = fmaxf(fmaxf(t8[0], t8[2]), fmaxf(t8[1], t8[3]));
  // independent exps + tree sums
  float es[16];
#pragma unroll
  for (int j = 0; j < 16; j++) es[j] = __expf(lg[j] - bm);
  float ss[8], aa[8];
#pragma unroll
  for (int j = 0; j < 8; j++) {
    ss[j] = es[j] + es[j + 8];
    aa[j] = es[j] * msg[j] + es[j + 8] * msg[j + 8];
  }
#pragma unroll
  for (int j = 0; j < 4; j++) { ss[j] += ss[j + 4]; aa[j] += aa[j + 4]; }
  float sB = (ss[0] + ss[2]) + (ss[1] + ss[3]);
  float aB = (aa[0] + aa[2]) + (aa[1] + aa[3]);
  // one online merge per batch
  float mn = fmaxf(m, bm);
  float sc = __expf(m - mn), sb = __expf(bm - mn);
  sum = sum * sc + sB * sb;
  acc = acc * sc + aB * sb;
  m = mn;
}

__global__ __launch_bounds__(320, 2) void k_layer(
    const float* __restrict__ uin, float* __restrict__ hc, float* __restrict__ uout,
    const float4* __restrict__ eattr_s, const int* __restrict__ src_s,
    const int* __restrict__ off,
    const float* __restrict__ W_edge, const float* __restrict__ b_edge,
    const float* __restrict__ tptr, int layer,
    const float* __restrict__ W1, const float* __restrict__ b1,
    const float* __restrict__ g1, const float* __restrict__ be1,
    const float* __restrict__ W2, const float* __restrict__ b2,
    const float* __restrict__ lng, const float* __restrict__ lnb,
    int addRes, int writeU) {
  __shared__ float sW[64 * 128];   // 32KB W1 [k][j]
  __shared__ float sW2[128 * 64];  // 32KB W2 [k][i]
  __shared__ float sZ[128 * 21];   // 10.5KB: h rows 0..63 [k][n]; then z rows 0..127 [j][n]

  int tid = threadIdx.x;
  int lane = tid & 63;
  int wv = tid >> 6;  // 0..4
  int t0 = blockIdx.x * TILE;
  int n0 = wv * 4;

  // ---- issue weight loads (held in regs through phase 1) ----
  float4 wA[7], wB[7];
#pragma unroll
  for (int i = 0; i < 7; i++) {
    int idx = tid + 320 * i;
    if (idx < 2048) {
      wA[i] = ((const float4*)W1)[idx];
      wB[i] = ((const float4*)W2)[idx];
    }
  }

  // ---- phase 1: edge aggregation, 4 nodes per wave, batch-16 tree softmax ----
  {
    float tv = tptr[layer];
    float we0 = W_edge[lane], we1 = W_edge[64 + lane], we2 = W_edge[128 + lane],
          we3 = W_edge[192 + lane];
    float be = b_edge[lane];
#pragma unroll
    for (int q = 0; q < 4; q++) {
      int gn = t0 + n0 + q;
      int a = off[gn], d = off[gn + 1] - a;
      float un = uin[(gn << 6) + lane];
      float m = NEG_INF, sum = 0.f, acc = 0.f;
      int nfull = d & ~15;
      for (int i = 0; i < nfull; i += 16)
        agg_batch<false>(src_s, eattr_s, uin, a + i, 16, lane, be, we0, we1, we2, we3, tv,
                         m, sum, acc);
      int rem = d - nfull;
      if (rem)
        agg_batch<true>(src_s, eattr_s, uin, a + nfull, rem, lane, be, we0, we1, we2, we3, tv,
                        m, sum, acc);
      sZ[lane * 21 + n0 + q] = acc / (sum + 1e-16f) + un;  // h = agg + x
    }
  }

  // ---- stage weights to LDS, single barrier ----
#pragma unroll
  for (int i = 0; i < 7; i++) {
    int idx = tid + 320 * i;
    if (idx < 2048) {
      ((float4*)sW)[idx] = wA[i];
      ((float4*)sW2)[idx] = wB[i];
    }
  }
  __syncthreads();  // the only barrier

  // ---- GEMM1: 4 nodes x 2 cols per lane (cols 2*lane, 2*lane+1) ----
  int j0 = 2 * lane;
  float2 b1v = *((const float2*)&b1[j0]);
  float ac[4][2];
#pragma unroll
  for (int q = 0; q < 4; q++) { ac[q][0] = b1v.x; ac[q][1] = b1v.y; }
#pragma unroll 8
  for (int k = 0; k < 64; k++) {
    float4 hv = *((float4*)&sZ[k * 21 + n0]);     // wave-uniform addr: broadcast
    float2 wv2 = *((float2*)&sW[k * 128 + j0]);
    ac[0][0] += hv.x * wv2.x; ac[0][1] += hv.x * wv2.y;
    ac[1][0] += hv.y * wv2.x; ac[1][1] += hv.y * wv2.y;
    ac[2][0] += hv.z * wv2.x; ac[2][1] += hv.z * wv2.y;
    ac[3][0] += hv.w * wv2.x; ac[3][1] += hv.w * wv2.y;
  }

  // ---- LN1 (over 128) via wave shuffle; write z to LDS ----
  {
    float2 gv = *((const float2*)&g1[j0]);
    float2 bev = *((const float2*)&be1[j0]);
    float4 zlo, zhi;
    float* zl = &zlo.x;
    float* zh = &zhi.x;
#pragma unroll
    for (int q = 0; q < 4; q++) {
      float s = ac[q][0] + ac[q][1];
      float sq = ac[q][0] * ac[q][0] + ac[q][1] * ac[q][1];
#pragma unroll
      for (int o = 32; o; o >>= 1) { s += __shfl_xor(s, o); sq += __shfl_xor(sq, o); }
      float mu = s * (1.f / 128.f);
      float var = sq * (1.f / 128.f) - mu * mu;
      float rs = rsqrtf(var + 1e-5f);
      zl[q] = fmaxf((ac[q][0] - mu) * rs * gv.x + bev.x, 0.f);
      zh[q] = fmaxf((ac[q][1] - mu) * rs * gv.y + bev.y, 0.f);
    }
    // z[j][n]: this wave's columns only -> within-wave dependency, no barrier
    *((float4*)&sZ[(j0 + 0) * 21 + n0]) = zlo;
    *((float4*)&sZ[(j0 + 1) * 21 + n0]) = zhi;
  }

  // ---- GEMM2: 4 nodes x 1 col per lane (col = lane) ----
  float bo = b2[lane];
  float o4[4] = {bo, bo, bo, bo};
#pragma unroll 8
  for (int k = 0; k < 128; k++) {
    float4 zv = *((float4*)&sZ[k * 21 + n0]);     // wave-uniform addr: broadcast
    float wv2 = sW2[k * 64 + lane];
    o4[0] += zv.x * wv2;
    o4[1] += zv.y * wv2;
    o4[2] += zv.z * wv2;
    o4[3] += zv.w * wv2;
  }

  // ---- residual + hc write ----
  float hcn[4];
#pragma unroll
  for (int q = 0; q < 4; q++) {
    int gn = t0 + n0 + q;
    float r = addRes ? hc[gn * 64 + lane] : 0.f;
    float hv = o4[q] + r;
    hc[gn * 64 + lane] = hv;
    hcn[q] = hv;
  }

  // ---- next-layer pre-LN: uout = relu(LN(hc)) via wave shuffle ----
  if (writeU) {
    float lg_ = lng[lane], lb_ = lnb[lane];
#pragma unroll
    for (int q = 0; q < 4; q++) {
      float s = hcn[q], sq = hcn[q] * hcn[q];
#pragma unroll
      for (int o = 32; o; o >>= 1) { s += __shfl_xor(s, o); sq += __shfl_xor(sq, o); }
      float mu = s * (1.f / 64.f);
      float var = sq * (1.f / 64.f) - mu * mu;
      float rs = rsqrtf(var + 1e-5f);
      uout[(t0 + n0 + q) * 64 + lane] = fmaxf((hcn[q] - mu) * rs * lg_ + lb_, 0.f);
    }
  }
}

// ---------------- final: out = relu(LN(hc, g0, b0)) @ W_out + b_out ----------------

__global__ __launch_bounds__(256) void k_final(const float* __restrict__ hc, const float* __restrict__ g,
                                               const float* __restrict__ bptr, const float* __restrict__ Wout,
                                               const float* __restrict__ bout, float* __restrict__ out) {
  __shared__ float sW[DIM * DIM];
  int tid = threadIdx.x;
  for (int i = tid; i < 1024; i += 256) ((float4*)sW)[i] = ((const float4*)Wout)[i];
  __syncthreads();
  int lane = tid & 63, w = tid >> 6;
  int n = blockIdx.x * 4 + w;
  if (n >= N_NODES) return;
  float v = hc[n * 64 + lane];
  float s = v, q = v * v;
#pragma unroll
  for (int o = 32; o; o >>= 1) { s += __shfl_xor(s, o); q += __shfl_xor(q, o); }
  float mu = s * (1.f / 64.f);
  float var = q * (1.f / 64.f) - mu * mu;
  float rs = rsqrtf(var + 1e-5f);
  float z = fmaxf((v - mu) * rs * g[lane] + bptr[lane], 0.f);
  float acc = bout[lane];
  for (int k = 0; k < 64; k++) {
    float zk = __shfl(z, k);
    acc += zk * sW[k * 64 + lane];
  }
  out[n * 64 + lane] = acc;
}

// ---------------- host ----------------

extern "C" void kernel_launch(void* const* d_in, const int* in_sizes, int n_in,
                              void* d_out, int out_size, void* d_ws, size_t ws_size,
                              hipStream_t stream) {
  const float* x        = (const float*)d_in[0];
  const float* eattr    = (const float*)d_in[1];
  const int*   src      = (const int*)d_in[2];
  const int*   dst      = (const int*)d_in[3];
  const float* W_node   = (const float*)d_in[4];
  const float* b_node   = (const float*)d_in[5];
  const float* W_edge   = (const float*)d_in[6];
  const float* b_edge   = (const float*)d_in[7];
  const float* t        = (const float*)d_in[8];
  const float* W1       = (const float*)d_in[9];
  const float* b1       = (const float*)d_in[10];
  const float* g1       = (const float*)d_in[11];
  const float* be1      = (const float*)d_in[12];
  const float* W2       = (const float*)d_in[13];
  const float* b2       = (const float*)d_in[14];
  const float* ln_g     = (const float*)d_in[15];
  const float* ln_b     = (const float*)d_in[16];
  const float* W_out    = (const float*)d_in[17];
  const float* b_out    = (const float*)d_in[18];
  float* out = (float*)d_out;

  char* w = (char*)d_ws;
  float* uA      = (float*)w;  w += (size_t)N_NODES * 64 * 4;
  float* uB      = (float*)w;  w += (size_t)N_NODES * 64 * 4;
  float* hcb     = (float*)w;  w += (size_t)N_NODES * 64 * 4;
  int* off       = (int*)w;    w += (size_t)(N_NODES + 1) * 4;
  int* cur       = (int*)w;    w += (size_t)N_NODES * 4;
  int* eids      = (int*)w;    w += (size_t)N_EDGES * 4;
  int* src_s     = (int*)w;    w += (size_t)N_EDGES * 4;
  float4* eattr_s = (float4*)w; w += (size_t)N_EDGES * 16;

  k_zero<<<(N_NODES + 255) / 256, 256, 0, stream>>>(cur, N_NODES);
  k_hist<<<(N_EDGES + 255) / 256, 256, 0, stream>>>(dst, cur);
  k_scan<<<1, 256, 0, stream>>>(cur, off);
  k_scatter<<<(N_EDGES + 255) / 256, 256, 0, stream>>>(dst, cur, eids);
  k_sortgather<<<(N_NODES + 3) / 4, 256, 0, stream>>>(off, eids, src, (const float4*)eattr,
                                                      src_s, eattr_s);

  k_enc<<<(N_NODES * 64 + 255) / 256, 256, 0, stream>>>(x, W_node, b_node, hcb, uA);

  for (int l = 0; l < LAYERS; l++) {
    const float* uin = (l & 1) ? uB : uA;
    float* uo        = (l & 1) ? uA : uB;
    int nxt = (l + 1 < LAYERS) ? (l + 1) : 0;  // unused when writeU=0
    k_layer<<<NBLK, 320, 0, stream>>>(uin, hcb, uo, eattr_s, src_s, off,
                                      W_edge, b_edge, t, l,
                                      W1 + (size_t)l * DIM * HID, b1 + (size_t)l * HID,
                                      g1 + (size_t)l * HID, be1 + (size_t)l * HID,
                                      W2 + (size_t)l * HID * DIM, b2 + (size_t)l * DIM,
                                      ln_g + (size_t)nxt * DIM, ln_b + (size_t)nxt * DIM,
                                      (l > 0) ? 1 : 0, (l < LAYERS - 1) ? 1 : 0);
  }

  k_final<<<(N_NODES + 3) / 4, 256, 0, stream>>>(hcb, ln_g, ln_b, W_out, b_out, out);
}

// Round 5
// 1230.290 us; speedup vs baseline: 1.6116x; 1.6116x over previous
//
#include <hip/hip_runtime.h>

#define N_NODES 10000
#define N_EDGES 160000
#define NUM_FEAT 14
#define EDGE_DIM 4
#define DIM 64
#define HID 128
#define LAYERS 28

#define NEG_INF (-__builtin_inff())

// ---------------- CSR build ----------------

__global__ __launch_bounds__(256) void k_zero(int* __restrict__ p, int n) {
  int i = blockIdx.x * 256 + threadIdx.x;
  if (i < n) p[i] = 0;
}

__global__ __launch_bounds__(256) void k_hist(const int* __restrict__ dst, int* __restrict__ cur) {
  int e = blockIdx.x * 256 + threadIdx.x;
  if (e < N_EDGES) atomicAdd(&cur[dst[e]], 1);
}

__global__ __launch_bounds__(256) void k_scan(int* __restrict__ cur, int* __restrict__ off) {
  __shared__ int part[256];
  int t = threadIdx.x;
  const int CH = 40;
  int base = t * CH;
  int s = 0;
  for (int i = 0; i < CH; i++) {
    int idx = base + i;
    if (idx < N_NODES) s += cur[idx];
  }
  part[t] = s;
  __syncthreads();
  for (int ofs = 1; ofs < 256; ofs <<= 1) {
    int tmp = (t >= ofs) ? part[t - ofs] : 0;
    __syncthreads();
    part[t] += tmp;
    __syncthreads();
  }
  int run = part[t] - s;
  for (int i = 0; i < CH; i++) {
    int idx = base + i;
    if (idx < N_NODES) {
      int d = cur[idx];
      off[idx] = run;
      cur[idx] = run;
      run += d;
    }
  }
  if (t == 255) off[N_NODES] = part[255];
}

__global__ __launch_bounds__(256) void k_scatter(const int* __restrict__ dst, int* __restrict__ cur,
                                                 int* __restrict__ eids) {
  int e = blockIdx.x * 256 + threadIdx.x;
  if (e < N_EDGES) {
    int p = atomicAdd(&cur[dst[e]], 1);
    eids[p] = e;
  }
}

// wave-per-node bitonic sort of edge ids, then gather src/eattr into slot order.
__global__ __launch_bounds__(256) void k_sortgather(
    const int* __restrict__ off, const int* __restrict__ eids,
    const int* __restrict__ src, const float4* __restrict__ eattr,
    int* __restrict__ src_s, float4* __restrict__ eattr_s) {
  int node = blockIdx.x * 4 + (threadIdx.x >> 6);
  int lane = threadIdx.x & 63;
  if (node >= N_NODES) return;
  int a = off[node];
  int d = off[node + 1] - a;
  if (d <= 64) {
    int key = (lane < d) ? eids[a + lane] : 0x7fffffff;
#pragma unroll
    for (int k = 2; k <= 64; k <<= 1) {
      for (int j = k >> 1; j > 0; j >>= 1) {
        int p = __shfl_xor(key, j);
        bool dirUp = ((lane & k) == 0);
        bool isLower = ((lane & j) == 0);
        key = ((isLower == dirUp) ? min(key, p) : max(key, p));
      }
    }
    if (lane < d) {
      int e = key;
      src_s[a + lane] = src[e];
      eattr_s[a + lane] = eattr[e];
    }
  } else {
    for (int i = lane; i < d; i += 64) {
      int e = eids[a + i];
      int r = 0;
      for (int j = 0; j < d; j++) r += (eids[a + j] < e) ? 1 : 0;
      src_s[a + r] = src[e];
      eattr_s[a + r] = eattr[e];
    }
  }
}

// ---------------- node encoder ----------------

__global__ __launch_bounds__(256) void k_enc(const float* __restrict__ x, const float* __restrict__ Wn,
                                             const float* __restrict__ bn, float* __restrict__ hc,
                                             float* __restrict__ u) {
  int gid = blockIdx.x * 256 + threadIdx.x;
  if (gid >= N_NODES * DIM) return;
  int n = gid >> 6, j = gid & 63;
  float acc = bn[j];
#pragma unroll
  for (int k = 0; k < NUM_FEAT; k++) acc += x[n * NUM_FEAT + k] * Wn[k * DIM + j];
  hc[gid] = acc;
  u[gid] = acc;
}

// ---------------- edge aggregation: 1 node/wave, batch-16 tree softmax ----------------

template <bool GUARD>
__device__ __forceinline__ void agg_batch(
    const int* __restrict__ src_s, const float4* __restrict__ eattr_s,
    const float* __restrict__ uin, int base, int rem, int lane,
    float be, float we0, float we1, float we2, float we3, float tv,
    float& m, float& sum, float& acc) {
  float msg[16], lg[16];
#pragma unroll
  for (int j = 0; j < 16; j++) {
    if (!GUARD || j < rem) {
      int sn = src_s[base + j];
      float4 ev = eattr_s[base + j];
      float mv = fmaxf(uin[(sn << 6) + lane] + be + ev.x * we0 + ev.y * we1 +
                       ev.z * we2 + ev.w * we3, 0.f) + 1e-7f;
      msg[j] = mv;
      lg[j] = mv * tv;
    } else {
      msg[j] = 0.f;
      lg[j] = NEG_INF;
    }
  }
  float t8[8];
#pragma unroll
  for (int j = 0; j < 8; j++) t8[j] = fmaxf(lg[j], lg[j + 8]);
#pragma unroll
  for (int j = 0; j < 4; j++) t8[j] = fmaxf(t8[j], t8[j + 4]);
  float bm = fmaxf(fmaxf(t8[0], t8[2]), fmaxf(t8[1], t8[3]));
  float es[16];
#pragma unroll
  for (int j = 0; j < 16; j++) es[j] = __expf(lg[j] - bm);
  float ss[8], aa[8];
#pragma unroll
  for (int j = 0; j < 8; j++) {
    ss[j] = es[j] + es[j + 8];
    aa[j] = es[j] * msg[j] + es[j + 8] * msg[j + 8];
  }
#pragma unroll
  for (int j = 0; j < 4; j++) { ss[j] += ss[j + 4]; aa[j] += aa[j + 4]; }
  float sB = (ss[0] + ss[2]) + (ss[1] + ss[3]);
  float aB = (aa[0] + aa[2]) + (aa[1] + aa[3]);
  float mn = fmaxf(m, bm);
  float sc = __expf(m - mn), sb = __expf(bm - mn);
  sum = sum * sc + sB * sb;
  acc = acc * sc + aB * sb;
  m = mn;
}

__global__ __launch_bounds__(256) void k_edge(
    const float* __restrict__ uin, const float4* __restrict__ eattr_s,
    const int* __restrict__ src_s,
    const float* __restrict__ W_edge, const float* __restrict__ b_edge,
    const int* __restrict__ off,
    const float* __restrict__ tptr, int layer, float* __restrict__ htmp) {
  int node = (blockIdx.x << 2) + (threadIdx.x >> 6);
  int lane = threadIdx.x & 63;
  if (node >= N_NODES) return;
  float tv = tptr[layer];
  float we0 = W_edge[lane], we1 = W_edge[64 + lane], we2 = W_edge[128 + lane],
        we3 = W_edge[192 + lane];
  float be = b_edge[lane];
  int a = off[node], d = off[node + 1] - a;
  float un = uin[(node << 6) + lane];
  float m = NEG_INF, sum = 0.f, acc = 0.f;
  int nfull = d & ~15;
  for (int i = 0; i < nfull; i += 16)
    agg_batch<false>(src_s, eattr_s, uin, a + i, 16, lane, be, we0, we1, we2, we3, tv,
                     m, sum, acc);
  int rem = d - nfull;
  if (rem)
    agg_batch<true>(src_s, eattr_s, uin, a + nfull, rem, lane, be, we0, we1, we2, we3, tv,
                    m, sum, acc);
  htmp[(node << 6) + lane] = acc / (sum + 1e-16f) + un;
}

// ---------------- MLP: 512 threads (8 waves), 2 nodes/wave, 16 nodes/block ----------------
// W1/W2 in LDS shared by 8 waves. Per-wave h/z rows node-interleaved so GEMM
// inner loops use wave-uniform broadcast b64 reads (h/z) + bank-distributed
// b64/b32 reads (W). LayerNorms via shfl_xor; no barrier after weight staging.

#define MBLK (N_NODES / 16)  // 625, exact

__global__ __launch_bounds__(512, 4) void k_mlp2(
    const float* __restrict__ hin, float* __restrict__ hc, float* __restrict__ uout,
    const float* __restrict__ W1, const float* __restrict__ b1,
    const float* __restrict__ g1, const float* __restrict__ be1,
    const float* __restrict__ W2, const float* __restrict__ b2,
    const float* __restrict__ lng, const float* __restrict__ lnb,
    int addRes, int writeU) {
  __shared__ float sW1[64 * 128];   // 32KB [k][j]
  __shared__ float sW2[128 * 64];   // 32KB [k][i]
  __shared__ float sH[8][128];      // 4KB: per wave, h interleaved (k*2 + node)
  __shared__ float sZ[8][256];      // 8KB: per wave, z interleaved (k*2 + node)

  int tid = threadIdx.x;
  int lane = tid & 63;
  int wv = tid >> 6;  // 0..7
  int gn0 = blockIdx.x * 16 + wv * 2;
  int gn1 = gn0 + 1;

  // stage weights
  for (int i = tid; i < 2048; i += 512) ((float4*)sW1)[i] = ((const float4*)W1)[i];
  for (int i = tid; i < 2048; i += 512) ((float4*)sW2)[i] = ((const float4*)W2)[i];

  // load h rows, write interleaved pair (within-wave visibility only)
  {
    float h0 = hin[gn0 * 64 + lane];
    float h1 = hin[gn1 * 64 + lane];
    *((float2*)&sH[wv][lane * 2]) = make_float2(h0, h1);
  }
  __syncthreads();  // weights ready (sH is within-wave)

  // ---- GEMM1: cols j0=2*lane, j0+1; 2 nodes ----
  int j0 = 2 * lane;
  float2 b1v = *((const float2*)&b1[j0]);
  float a00 = b1v.x, a01 = b1v.y, a10 = b1v.x, a11 = b1v.y;
#pragma unroll 8
  for (int k = 0; k < 64; k++) {
    float2 hp = *((float2*)&sH[wv][k * 2]);        // broadcast
    float2 wp = *((float2*)&sW1[k * 128 + j0]);    // 4 lanes/bank-pair: no excess conflict
    a00 += hp.x * wp.x; a01 += hp.x * wp.y;
    a10 += hp.y * wp.x; a11 += hp.y * wp.y;
  }

  // ---- LN1 (over 128) via shfl; z -> LDS interleaved ----
  {
    float2 gv = *((const float2*)&g1[j0]);
    float2 bev = *((const float2*)&be1[j0]);
    float s0 = a00 + a01, q0 = a00 * a00 + a01 * a01;
    float s1 = a10 + a11, q1 = a10 * a10 + a11 * a11;
#pragma unroll
    for (int o = 32; o; o >>= 1) {
      s0 += __shfl_xor(s0, o); q0 += __shfl_xor(q0, o);
      s1 += __shfl_xor(s1, o); q1 += __shfl_xor(q1, o);
    }
    float mu0 = s0 * (1.f / 128.f), mu1 = s1 * (1.f / 128.f);
    float rs0 = rsqrtf(q0 * (1.f / 128.f) - mu0 * mu0 + 1e-5f);
    float rs1 = rsqrtf(q1 * (1.f / 128.f) - mu1 * mu1 + 1e-5f);
    float4 zv;
    zv.x = fmaxf((a00 - mu0) * rs0 * gv.x + bev.x, 0.f);  // (col j0,   node0)
    zv.y = fmaxf((a10 - mu1) * rs1 * gv.x + bev.x, 0.f);  // (col j0,   node1)
    zv.z = fmaxf((a01 - mu0) * rs0 * gv.y + bev.y, 0.f);  // (col j0+1, node0)
    zv.w = fmaxf((a11 - mu1) * rs1 * gv.y + bev.y, 0.f);  // (col j0+1, node1)
    *((float4*)&sZ[wv][4 * lane]) = zv;  // within-wave
  }

  // ---- GEMM2: col i=lane; 2 nodes ----
  float bo = b2[lane];
  float o0 = bo, o1 = bo;
#pragma unroll 8
  for (int k = 0; k < 128; k++) {
    float2 zp = *((float2*)&sZ[wv][k * 2]);  // broadcast
    float wv2 = sW2[k * 64 + lane];          // 2 lanes/bank: free
    o0 += zp.x * wv2;
    o1 += zp.y * wv2;
  }

  // ---- residual + hc write ----
  float r0 = addRes ? hc[gn0 * 64 + lane] : 0.f;
  float r1 = addRes ? hc[gn1 * 64 + lane] : 0.f;
  float hcn0 = o0 + r0, hcn1 = o1 + r1;
  hc[gn0 * 64 + lane] = hcn0;
  hc[gn1 * 64 + lane] = hcn1;

  // ---- next-layer pre-LN: uout = relu(LN(hc)) via shfl ----
  if (writeU) {
    float lg_ = lng[lane], lb_ = lnb[lane];
    float s0 = hcn0, q0 = hcn0 * hcn0;
    float s1 = hcn1, q1 = hcn1 * hcn1;
#pragma unroll
    for (int o = 32; o; o >>= 1) {
      s0 += __shfl_xor(s0, o); q0 += __shfl_xor(q0, o);
      s1 += __shfl_xor(s1, o); q1 += __shfl_xor(q1, o);
    }
    float mu0 = s0 * (1.f / 64.f), mu1 = s1 * (1.f / 64.f);
    float rs0 = rsqrtf(q0 * (1.f / 64.f) - mu0 * mu0 + 1e-5f);
    float rs1 = rsqrtf(q1 * (1.f / 64.f) - mu1 * mu1 + 1e-5f);
    uout[gn0 * 64 + lane] = fmaxf((hcn0 - mu0) * rs0 * lg_ + lb_, 0.f);
    uout[gn1 * 64 + lane] = fmaxf((hcn1 - mu1) * rs1 * lg_ + lb_, 0.f);
  }
}

// ---------------- final: out = relu(LN(hc, g0, b0)) @ W_out + b_out ----------------

__global__ __launch_bounds__(256) void k_final(const float* __restrict__ hc, const float* __restrict__ g,
                                               const float* __restrict__ bptr, const float* __restrict__ Wout,
                                               const float* __restrict__ bout, float* __restrict__ out) {
  __shared__ float sW[DIM * DIM];
  int tid = threadIdx.x;
  for (int i = tid; i < 1024; i += 256) ((float4*)sW)[i] = ((const float4*)Wout)[i];
  __syncthreads();
  int lane = tid & 63, w = tid >> 6;
  int n = blockIdx.x * 4 + w;
  if (n >= N_NODES) return;
  float v = hc[n * 64 + lane];
  float s = v, q = v * v;
#pragma unroll
  for (int o = 32; o; o >>= 1) { s += __shfl_xor(s, o); q += __shfl_xor(q, o); }
  float mu = s * (1.f / 64.f);
  float var = q * (1.f / 64.f) - mu * mu;
  float rs = rsqrtf(var + 1e-5f);
  float z = fmaxf((v - mu) * rs * g[lane] + bptr[lane], 0.f);
  float acc = bout[lane];
  for (int k = 0; k < 64; k++) {
    float zk = __shfl(z, k);
    acc += zk * sW[k * 64 + lane];
  }
  out[n * 64 + lane] = acc;
}

// ---------------- host ----------------

extern "C" void kernel_launch(void* const* d_in, const int* in_sizes, int n_in,
                              void* d_out, int out_size, void* d_ws, size_t ws_size,
                              hipStream_t stream) {
  const float* x        = (const float*)d_in[0];
  const float* eattr    = (const float*)d_in[1];
  const int*   src      = (const int*)d_in[2];
  const int*   dst      = (const int*)d_in[3];
  const float* W_node   = (const float*)d_in[4];
  const float* b_node   = (const float*)d_in[5];
  const float* W_edge   = (const float*)d_in[6];
  const float* b_edge   = (const float*)d_in[7];
  const float* t        = (const float*)d_in[8];
  const float* W1       = (const float*)d_in[9];
  const float* b1       = (const float*)d_in[10];
  const float* g1       = (const float*)d_in[11];
  const float* be1      = (const float*)d_in[12];
  const float* W2       = (const float*)d_in[13];
  const float* b2       = (const float*)d_in[14];
  const float* ln_g     = (const float*)d_in[15];
  const float* ln_b     = (const float*)d_in[16];
  const float* W_out    = (const float*)d_in[17];
  const float* b_out    = (const float*)d_in[18];
  float* out = (float*)d_out;

  char* w = (char*)d_ws;
  float* u       = (float*)w;  w += (size_t)N_NODES * 64 * 4;
  float* hcb     = (float*)w;  w += (size_t)N_NODES * 64 * 4;
  float* htmp    = (float*)w;  w += (size_t)N_NODES * 64 * 4;
  int* off       = (int*)w;    w += (size_t)(N_NODES + 1) * 4;
  int* cur       = (int*)w;    w += (size_t)N_NODES * 4;
  int* eids      = (int*)w;    w += (size_t)N_EDGES * 4;
  int* src_s     = (int*)w;    w += (size_t)N_EDGES * 4;
  float4* eattr_s = (float4*)w; w += (size_t)N_EDGES * 16;

  k_zero<<<(N_NODES + 255) / 256, 256, 0, stream>>>(cur, N_NODES);
  k_hist<<<(N_EDGES + 255) / 256, 256, 0, stream>>>(dst, cur);
  k_scan<<<1, 256, 0, stream>>>(cur, off);
  k_scatter<<<(N_EDGES + 255) / 256, 256, 0, stream>>>(dst, cur, eids);
  k_sortgather<<<(N_NODES + 3) / 4, 256, 0, stream>>>(off, eids, src, (const float4*)eattr,
                                                      src_s, eattr_s);

  k_enc<<<(N_NODES * 64 + 255) / 256, 256, 0, stream>>>(x, W_node, b_node, hcb, u);

  for (int l = 0; l < LAYERS; l++) {
    k_edge<<<(N_NODES + 3) / 4, 256, 0, stream>>>(u, eattr_s, src_s, W_edge, b_edge,
                                                  off, t, l, htmp);
    int nxt = (l + 1 < LAYERS) ? (l + 1) : 0;  // unused when writeU=0
    k_mlp2<<<MBLK, 512, 0, stream>>>(htmp, hcb, u,
                                     W1 + (size_t)l * DIM * HID, b1 + (size_t)l * HID,
                                     g1 + (size_t)l * HID, be1 + (size_t)l * HID,
                                     W2 + (size_t)l * HID * DIM, b2 + (size_t)l * DIM,
                                     ln_g + (size_t)nxt * DIM, ln_b + (size_t)nxt * DIM,
                                     (l > 0) ? 1 : 0, (l < LAYERS - 1) ? 1 : 0);
  }

  k_final<<<(N_NODES + 3) / 4, 256, 0, stream>>>(hcb, ln_g, ln_b, W_out, b_out, out);
}